// Round 6
// baseline (222.165 us; speedup 1.0000x reference)
//
#include <hip/hip_runtime.h>
#include <hip/hip_fp16.h>

typedef _Float16 f16x8 __attribute__((ext_vector_type(8)));
typedef _Float16 f16x4 __attribute__((ext_vector_type(4)));
typedef float    f32x4 __attribute__((ext_vector_type(4)));

constexpr int NN = 50000;        // nodes
constexpr int NE = 800000;       // edges (before self-loops)
constexpr int ET = NE + NN;      // edges + self-loops
constexpr int IC = 128;          // in channels
constexpr int HC = 256;          // heads * out_ch
constexpr int OC = 64;           // out channels

// ---------------------------------------------------------------------------
// Prep: Wt[m][k] = lin_w[k][m] as fp16 (A-operand, L2-resident 64KB)
// ---------------------------------------------------------------------------
__global__ void prep_wt(const float* __restrict__ w, __half* __restrict__ wt)
{
    const int k = blockIdx.x;      // 128
    const int m = threadIdx.x;     // 256
    wt[m * IC + k] = __float2half(w[k * HC + m]);
}

// ---------------------------------------------------------------------------
// Proj via MFMA + fused per-head logits. Output staged through LDS so global
// stores are full 512B node-rows (was: 8B lanes at 512B stride, ~2x write amp).
// ---------------------------------------------------------------------------
__global__ __launch_bounds__(256) void proj_mfma(
    const float* __restrict__ feat, const __half* __restrict__ wt,
    const float* __restrict__ att_s, const float* __restrict__ att_d,
    __half* __restrict__ Xh, float* __restrict__ As, float* __restrict__ Ad)
{
    __shared__ _Float16 sf[64 * 128];        // input tile
    __shared__ _Float16 so[64 * 260];        // output stage (+4ch pad: bank spread)
    const int t  = threadIdx.x;
    const int w  = t >> 6;
    const int l  = t & 63;
    const int n0 = blockIdx.x * 64;

    // cooperative load: thread t covers 16B-chunks 4*(t&3)..+3 of row t>>2
    {
        const int r  = t >> 2;
        const int gr = min(n0 + r, NN - 1);
        const float* src = feat + (size_t)gr * IC + (t & 3) * 32;
#pragma unroll
        for (int i = 0; i < 4; ++i) {
            const float4 f0 = *reinterpret_cast<const float4*>(src + i * 8);
            const float4 f1 = *reinterpret_cast<const float4*>(src + i * 8 + 4);
            f16x8 hv;
            hv[0] = (_Float16)f0.x; hv[1] = (_Float16)f0.y;
            hv[2] = (_Float16)f0.z; hv[3] = (_Float16)f0.w;
            hv[4] = (_Float16)f1.x; hv[5] = (_Float16)f1.y;
            hv[6] = (_Float16)f1.z; hv[7] = (_Float16)f1.w;
            const int cc = (t & 3) * 4 + i;
            *reinterpret_cast<f16x8*>(&sf[(r * 16 + (cc ^ (r & 7))) * 8]) = hv;
        }
    }
    __syncthreads();

    const int lhi = l >> 4, llo = l & 15;
    f32x4 acc[4][4] = {};   // [mg(channel)][ng(node)]

#pragma unroll
    for (int ks = 0; ks < 4; ++ks) {
        f16x8 a[4], b[4];
#pragma unroll
        for (int mg = 0; mg < 4; ++mg) {
            const int row = w * 64 + mg * 16 + llo;            // channel
            a[mg] = *reinterpret_cast<const f16x8*>(
                wt + (size_t)row * IC + ks * 32 + lhi * 8);
        }
#pragma unroll
        for (int ng = 0; ng < 4; ++ng) {
            const int rr = ng * 16 + llo;                      // node in tile
            const int cc = ks * 4 + lhi;
            b[ng] = *reinterpret_cast<const f16x8*>(
                &sf[(rr * 16 + (cc ^ (rr & 7))) * 8]);
        }
#pragma unroll
        for (int mg = 0; mg < 4; ++mg)
#pragma unroll
            for (int ng = 0; ng < 4; ++ng)
                acc[mg][ng] = __builtin_amdgcn_mfma_f32_16x16x32_f16(
                    a[mg], b[ng], acc[mg][ng], 0, 0, 0);
    }

    // att vectors for this lane's channel slots (reused across ng)
    float4 avs[4], avd[4];
#pragma unroll
    for (int mg = 0; mg < 4; ++mg) {
        const int ch = w * 64 + mg * 16 + 4 * lhi;
        avs[mg] = *reinterpret_cast<const float4*>(att_s + ch);
        avd[mg] = *reinterpret_cast<const float4*>(att_d + ch);
    }

    // logits + stage D-fragments into LDS (node-major rows)
#pragma unroll
    for (int ng = 0; ng < 4; ++ng) {
        const int n = n0 + ng * 16 + llo;
        float ps = 0.f, pd = 0.f;
#pragma unroll
        for (int mg = 0; mg < 4; ++mg) {
            const f32x4 v = acc[mg][ng];
            ps += v[0] * avs[mg].x + v[1] * avs[mg].y
                + v[2] * avs[mg].z + v[3] * avs[mg].w;
            pd += v[0] * avd[mg].x + v[1] * avd[mg].y
                + v[2] * avd[mg].z + v[3] * avd[mg].w;
            f16x4 pk;
            pk[0] = (_Float16)v[0]; pk[1] = (_Float16)v[1];
            pk[2] = (_Float16)v[2]; pk[3] = (_Float16)v[3];
            *reinterpret_cast<f16x4*>(
                &so[(ng * 16 + llo) * 260 + w * 64 + mg * 16 + 4 * lhi]) = pk;
        }
        ps += __shfl_xor(ps, 16); ps += __shfl_xor(ps, 32);
        pd += __shfl_xor(pd, 16); pd += __shfl_xor(pd, 32);
        if (lhi == 0 && n < NN) {
            As[n * 4 + w] = ps;
            Ad[n * 4 + w] = pd;
        }
    }
    __syncthreads();

    // coalesced store: wave w streams node-rows w*16..w*16+15 (512B each)
#pragma unroll
    for (int rr = 0; rr < 16; ++rr) {
        const int r = w * 16 + rr;
        const int n = n0 + r;
        if (n < NN)
            *reinterpret_cast<f16x4*>(&Xh[(size_t)n * HC + 4 * l]) =
                *reinterpret_cast<const f16x4*>(&so[r * 260 + 4 * l]);
    }
}

// ---------------------------------------------------------------------------
// CSR build: histogram, hierarchical scan (3 small kernels), fill
// ---------------------------------------------------------------------------
__global__ __launch_bounds__(256) void hist_kernel(
    const int* __restrict__ ei, int* __restrict__ deg)
{
    const int e = blockIdx.x * 256 + threadIdx.x;
    if (e >= ET) return;
    const int d = (e < NE) ? ei[NE + e] : (e - NE);
    atomicAdd(&deg[d], 1);
}

__global__ __launch_bounds__(256) void scan1(
    const int* __restrict__ deg, int* __restrict__ rowptr, int* __restrict__ bsum)
{
    __shared__ int sh[256];
    const int t = threadIdx.x;
    const int base = blockIdx.x * 1024 + t * 4;
    int4 v = {0, 0, 0, 0};
    if (base + 3 < NN) v = *reinterpret_cast<const int4*>(deg + base);
    else {
        if (base     < NN) v.x = deg[base];
        if (base + 1 < NN) v.y = deg[base + 1];
        if (base + 2 < NN) v.z = deg[base + 2];
    }
    sh[t] = v.x + v.y + v.z + v.w;
    __syncthreads();
    for (int o = 1; o < 256; o <<= 1) {
        const int u = (t >= o) ? sh[t - o] : 0;
        __syncthreads();
        sh[t] += u;
        __syncthreads();
    }
    const int excl = t ? sh[t - 1] : 0;
    int4 e;
    e.x = excl; e.y = excl + v.x; e.z = e.y + v.y; e.w = e.z + v.z;
    if (base + 3 < NN) *reinterpret_cast<int4*>(rowptr + base) = e;
    else {
        if (base     < NN) rowptr[base]     = e.x;
        if (base + 1 < NN) rowptr[base + 1] = e.y;
        if (base + 2 < NN) rowptr[base + 2] = e.z;
    }
    if (t == 255) bsum[blockIdx.x] = sh[255];
}

__global__ void scan2(int* __restrict__ bsum, int* __restrict__ rowptr_end, int nb)
{
    const int t = threadIdx.x;   // 64
    const int v = (t < nb) ? bsum[t] : 0;
    int inc = v;
#pragma unroll
    for (int o = 1; o < 64; o <<= 1) {
        const int u = __shfl_up(inc, o);
        if (t >= o) inc += u;
    }
    if (t < nb) bsum[t] = inc - v;            // exclusive block offset
    if (t == 63) rowptr_end[0] = inc;         // total = ET
}

__global__ __launch_bounds__(256) void scan3(
    int* __restrict__ rowptr, const int* __restrict__ bsum, int* __restrict__ cursor)
{
    const int off  = bsum[blockIdx.x];
    const int base = blockIdx.x * 1024 + threadIdx.x * 4;
#pragma unroll
    for (int i = 0; i < 4; ++i) {
        const int idx = base + i;
        if (idx < NN) {
            const int r = rowptr[idx] + off;
            rowptr[idx] = r;
            cursor[idx] = r;
        }
    }
}

__global__ __launch_bounds__(256) void fill_kernel(
    const int* __restrict__ ei, int* __restrict__ cursor, int* __restrict__ csr_src)
{
    const int e = blockIdx.x * 256 + threadIdx.x;
    if (e == 0) { csr_src[ET] = 0; csr_src[ET + 1] = 0; }   // pipeline pad
    if (e >= ET) return;
    int s, d;
    if (e < NE) { s = ei[e]; d = ei[NE + e]; }
    else        { s = e - NE; d = s; }
    csr_src[atomicAdd(&cursor[d], 1)] = s;
}

// ---------------------------------------------------------------------------
// Gather: one wave per dst node; lane group h = lane>>4 handles only head h.
// Depth-2 register pipeline: at iter j, loads for j+1 (As, Xh via s from the
// previous stage) and the index for j+2 are in flight; compute uses registers
// loaded a full iteration earlier. csr_src padded -> no branches in loop.
// ---------------------------------------------------------------------------
__global__ __launch_bounds__(256) void gather_kernel(
    const int* __restrict__ rowptr, const int* __restrict__ csr_src,
    const float* __restrict__ As, const float* __restrict__ Ad,
    const __half* __restrict__ Xh, const float* __restrict__ bias,
    float* __restrict__ out)
{
    const int gid  = blockIdx.x * 256 + threadIdx.x;
    const int w    = gid >> 6;
    const int lane = gid & 63;
    if (w >= NN) return;

    const int beg = rowptr[w];
    const int end = rowptr[w + 1];
    const int h   = lane >> 4;

    const float adh = Ad[w * 4 + h];
    float4 acc = {0.f, 0.f, 0.f, 0.f};
    float den = 0.f;

    // prologue: stage A = edge beg, index for edge beg+1
    int    sA = csr_src[beg];                       // beg < ET always (deg>=1)
    float  aA = As[sA * 4 + h];
    float2 xA = *reinterpret_cast<const float2*>(Xh + (size_t)sA * HC + 4 * lane);
    int    sB = csr_src[beg + 1];                   // beg+1 <= ET (padded)

    for (int j = beg; j < end; ++j) {
        // issue loads for stage B (consumed next iter) + index for j+2
        const float  aB = As[sB * 4 + h];
        const float2 xB = *reinterpret_cast<const float2*>(
            Xh + (size_t)sB * HC + 4 * lane);
        const int    sC = csr_src[j + 2];           // j+2 <= ET+1 (padded)

        // compute stage A (registers from previous iteration)
        float lg = aA + adh;
        lg = lg > 0.f ? lg : 0.2f * lg;
        const float ex = __expf(lg);
        den += ex;
        const __half2* h2 = reinterpret_cast<const __half2*>(&xA);
        const float2 lo = __half22float2(h2[0]);
        const float2 hi = __half22float2(h2[1]);
        acc.x = fmaf(ex, lo.x, acc.x);
        acc.y = fmaf(ex, lo.y, acc.y);
        acc.z = fmaf(ex, hi.x, acc.z);
        acc.w = fmaf(ex, hi.y, acc.w);

        aA = aB; xA = xB; sB = sC;                  // rotate pipeline
    }

    const float inv = 0.25f * __frcp_rn(den);
    acc.x *= inv; acc.y *= inv; acc.z *= inv; acc.w *= inv;

    // sum across the 4 head-lane-groups (lanes l, l^16, l^32, l^48 share channels)
    acc.x += __shfl_xor(acc.x, 16); acc.x += __shfl_xor(acc.x, 32);
    acc.y += __shfl_xor(acc.y, 16); acc.y += __shfl_xor(acc.y, 32);
    acc.z += __shfl_xor(acc.z, 16); acc.z += __shfl_xor(acc.z, 32);
    acc.w += __shfl_xor(acc.w, 16); acc.w += __shfl_xor(acc.w, 32);

    if (lane < 16) {
        const float4 b = *reinterpret_cast<const float4*>(&bias[4 * lane]);
        float4 o;
        o.x = acc.x + b.x; o.y = acc.y + b.y;
        o.z = acc.z + b.z; o.w = acc.w + b.w;
        *reinterpret_cast<float4*>(&out[(size_t)w * OC + 4 * lane]) = o;
    }
}

extern "C" void kernel_launch(void* const* d_in, const int* in_sizes, int n_in,
                              void* d_out, int out_size, void* d_ws, size_t ws_size,
                              hipStream_t stream)
{
    const float* feat = (const float*)d_in[0];
    const int*   ei   = (const int*)d_in[1];
    const float* lw   = (const float*)d_in[2];
    const float* as   = (const float*)d_in[3];
    const float* ad   = (const float*)d_in[4];
    const float* bias = (const float*)d_in[5];
    float* out = (float*)d_out;

    constexpr int NSB = (NN + 1023) / 1024;   // 49 scan blocks

    char* ws = (char*)d_ws;
    __half* Xh     = (__half*)ws;  ws += (size_t)NN * HC * 2;
    __half* Wt     = (__half*)ws;  ws += (size_t)HC * IC * 2;
    float*  Asrc   = (float*)ws;   ws += (size_t)NN * 4 * 4;
    float*  Adst   = (float*)ws;   ws += (size_t)NN * 4 * 4;
    int*    deg    = (int*)ws;     ws += (size_t)NN * 4;      // zeroed
    int*    rowptr = (int*)ws;     ws += (size_t)(NN + 1) * 4;
    int*    cursor = (int*)ws;     ws += (size_t)NN * 4;
    int*    bsum   = (int*)ws;     ws += (size_t)64 * 4;
    int*    csrsrc = (int*)ws;     ws += (size_t)(ET + 2) * 4;

    (void)hipMemsetAsync(deg, 0, sizeof(int) * (size_t)NN, stream);

    prep_wt<<<IC, HC, 0, stream>>>(lw, Wt);
    proj_mfma<<<(NN + 63) / 64, 256, 0, stream>>>(feat, Wt, as, ad, Xh, Asrc, Adst);
    hist_kernel<<<(ET + 255) / 256, 256, 0, stream>>>(ei, deg);
    scan1<<<NSB, 256, 0, stream>>>(deg, rowptr, bsum);
    scan2<<<1, 64, 0, stream>>>(bsum, rowptr + NN, NSB);
    scan3<<<NSB, 256, 0, stream>>>(rowptr, bsum, cursor);
    fill_kernel<<<(ET + 255) / 256, 256, 0, stream>>>(ei, cursor, csrsrc);
    gather_kernel<<<(NN * 64 + 255) / 256, 256, 0, stream>>>(
        rowptr, csrsrc, Asrc, Adst, Xh, bias, out);
}

// Round 7
// 221.624 us; speedup vs baseline: 1.0024x; 1.0024x over previous
//
#include <hip/hip_runtime.h>
#include <hip/hip_fp16.h>

typedef _Float16 f16x8 __attribute__((ext_vector_type(8)));
typedef _Float16 f16x4 __attribute__((ext_vector_type(4)));
typedef float    f32x4 __attribute__((ext_vector_type(4)));

constexpr int NN = 50000;        // nodes
constexpr int NE = 800000;       // edges (before self-loops)
constexpr int ET = NE + NN;      // edges + self-loops
constexpr int IC = 128;          // in channels
constexpr int HC = 256;          // heads * out_ch
constexpr int OC = 64;           // out channels

// ---------------------------------------------------------------------------
// Prep: Wt[m][k] = lin_w[k][m] as fp16 (A-operand, L2-resident 64KB)
// ---------------------------------------------------------------------------
__global__ void prep_wt(const float* __restrict__ w, __half* __restrict__ wt)
{
    const int k = blockIdx.x;      // 128
    const int m = threadIdx.x;     // 256
    wt[m * IC + k] = __float2half(w[k * HC + m]);
}

// ---------------------------------------------------------------------------
// Proj via MFMA + fused per-head logits. Output staged through LDS so global
// stores are full 512B node-rows (was: 8B lanes at 512B stride, ~2x write amp).
// ---------------------------------------------------------------------------
__global__ __launch_bounds__(256) void proj_mfma(
    const float* __restrict__ feat, const __half* __restrict__ wt,
    const float* __restrict__ att_s, const float* __restrict__ att_d,
    __half* __restrict__ Xh, float* __restrict__ As, float* __restrict__ Ad)
{
    __shared__ _Float16 sf[64 * 128];        // input tile
    __shared__ _Float16 so[64 * 260];        // output stage (+4ch pad: bank spread)
    const int t  = threadIdx.x;
    const int w  = t >> 6;
    const int l  = t & 63;
    const int n0 = blockIdx.x * 64;

    // cooperative load: thread t covers 16B-chunks 4*(t&3)..+3 of row t>>2
    {
        const int r  = t >> 2;
        const int gr = min(n0 + r, NN - 1);
        const float* src = feat + (size_t)gr * IC + (t & 3) * 32;
#pragma unroll
        for (int i = 0; i < 4; ++i) {
            const float4 f0 = *reinterpret_cast<const float4*>(src + i * 8);
            const float4 f1 = *reinterpret_cast<const float4*>(src + i * 8 + 4);
            f16x8 hv;
            hv[0] = (_Float16)f0.x; hv[1] = (_Float16)f0.y;
            hv[2] = (_Float16)f0.z; hv[3] = (_Float16)f0.w;
            hv[4] = (_Float16)f1.x; hv[5] = (_Float16)f1.y;
            hv[6] = (_Float16)f1.z; hv[7] = (_Float16)f1.w;
            const int cc = (t & 3) * 4 + i;
            *reinterpret_cast<f16x8*>(&sf[(r * 16 + (cc ^ (r & 7))) * 8]) = hv;
        }
    }
    __syncthreads();

    const int lhi = l >> 4, llo = l & 15;
    f32x4 acc[4][4] = {};   // [mg(channel)][ng(node)]

#pragma unroll
    for (int ks = 0; ks < 4; ++ks) {
        f16x8 a[4], b[4];
#pragma unroll
        for (int mg = 0; mg < 4; ++mg) {
            const int row = w * 64 + mg * 16 + llo;            // channel
            a[mg] = *reinterpret_cast<const f16x8*>(
                wt + (size_t)row * IC + ks * 32 + lhi * 8);
        }
#pragma unroll
        for (int ng = 0; ng < 4; ++ng) {
            const int rr = ng * 16 + llo;                      // node in tile
            const int cc = ks * 4 + lhi;
            b[ng] = *reinterpret_cast<const f16x8*>(
                &sf[(rr * 16 + (cc ^ (rr & 7))) * 8]);
        }
#pragma unroll
        for (int mg = 0; mg < 4; ++mg)
#pragma unroll
            for (int ng = 0; ng < 4; ++ng)
                acc[mg][ng] = __builtin_amdgcn_mfma_f32_16x16x32_f16(
                    a[mg], b[ng], acc[mg][ng], 0, 0, 0);
    }

    // att vectors for this lane's channel slots (reused across ng)
    float4 avs[4], avd[4];
#pragma unroll
    for (int mg = 0; mg < 4; ++mg) {
        const int ch = w * 64 + mg * 16 + 4 * lhi;
        avs[mg] = *reinterpret_cast<const float4*>(att_s + ch);
        avd[mg] = *reinterpret_cast<const float4*>(att_d + ch);
    }

    // logits + stage D-fragments into LDS (node-major rows)
#pragma unroll
    for (int ng = 0; ng < 4; ++ng) {
        const int n = n0 + ng * 16 + llo;
        float ps = 0.f, pd = 0.f;
#pragma unroll
        for (int mg = 0; mg < 4; ++mg) {
            const f32x4 v = acc[mg][ng];
            ps += v[0] * avs[mg].x + v[1] * avs[mg].y
                + v[2] * avs[mg].z + v[3] * avs[mg].w;
            pd += v[0] * avd[mg].x + v[1] * avd[mg].y
                + v[2] * avd[mg].z + v[3] * avd[mg].w;
            f16x4 pk;
            pk[0] = (_Float16)v[0]; pk[1] = (_Float16)v[1];
            pk[2] = (_Float16)v[2]; pk[3] = (_Float16)v[3];
            *reinterpret_cast<f16x4*>(
                &so[(ng * 16 + llo) * 260 + w * 64 + mg * 16 + 4 * lhi]) = pk;
        }
        ps += __shfl_xor(ps, 16); ps += __shfl_xor(ps, 32);
        pd += __shfl_xor(pd, 16); pd += __shfl_xor(pd, 32);
        if (lhi == 0 && n < NN) {
            As[n * 4 + w] = ps;
            Ad[n * 4 + w] = pd;
        }
    }
    __syncthreads();

    // coalesced store: wave w streams node-rows w*16..w*16+15 (512B each)
#pragma unroll
    for (int rr = 0; rr < 16; ++rr) {
        const int r = w * 16 + rr;
        const int n = n0 + r;
        if (n < NN)
            *reinterpret_cast<f16x4*>(&Xh[(size_t)n * HC + 4 * l]) =
                *reinterpret_cast<const f16x4*>(&so[r * 260 + 4 * l]);
    }
}

// ---------------------------------------------------------------------------
// CSR build: histogram, hierarchical scan (3 small kernels), fill
// ---------------------------------------------------------------------------
__global__ __launch_bounds__(256) void hist_kernel(
    const int* __restrict__ ei, int* __restrict__ deg)
{
    const int e = blockIdx.x * 256 + threadIdx.x;
    if (e >= ET) return;
    const int d = (e < NE) ? ei[NE + e] : (e - NE);
    atomicAdd(&deg[d], 1);
}

__global__ __launch_bounds__(256) void scan1(
    const int* __restrict__ deg, int* __restrict__ rowptr, int* __restrict__ bsum)
{
    __shared__ int sh[256];
    const int t = threadIdx.x;
    const int base = blockIdx.x * 1024 + t * 4;
    int4 v = {0, 0, 0, 0};
    if (base + 3 < NN) v = *reinterpret_cast<const int4*>(deg + base);
    else {
        if (base     < NN) v.x = deg[base];
        if (base + 1 < NN) v.y = deg[base + 1];
        if (base + 2 < NN) v.z = deg[base + 2];
    }
    sh[t] = v.x + v.y + v.z + v.w;
    __syncthreads();
    for (int o = 1; o < 256; o <<= 1) {
        const int u = (t >= o) ? sh[t - o] : 0;
        __syncthreads();
        sh[t] += u;
        __syncthreads();
    }
    const int excl = t ? sh[t - 1] : 0;
    int4 e;
    e.x = excl; e.y = excl + v.x; e.z = e.y + v.y; e.w = e.z + v.z;
    if (base + 3 < NN) *reinterpret_cast<int4*>(rowptr + base) = e;
    else {
        if (base     < NN) rowptr[base]     = e.x;
        if (base + 1 < NN) rowptr[base + 1] = e.y;
        if (base + 2 < NN) rowptr[base + 2] = e.z;
    }
    if (t == 255) bsum[blockIdx.x] = sh[255];
}

__global__ void scan2(int* __restrict__ bsum, int* __restrict__ rowptr_end, int nb)
{
    const int t = threadIdx.x;   // 64
    const int v = (t < nb) ? bsum[t] : 0;
    int inc = v;
#pragma unroll
    for (int o = 1; o < 64; o <<= 1) {
        const int u = __shfl_up(inc, o);
        if (t >= o) inc += u;
    }
    if (t < nb) bsum[t] = inc - v;            // exclusive block offset
    if (t == 63) rowptr_end[0] = inc;         // total = ET
}

__global__ __launch_bounds__(256) void scan3(
    int* __restrict__ rowptr, const int* __restrict__ bsum, int* __restrict__ cursor)
{
    const int off  = bsum[blockIdx.x];
    const int base = blockIdx.x * 1024 + threadIdx.x * 4;
#pragma unroll
    for (int i = 0; i < 4; ++i) {
        const int idx = base + i;
        if (idx < NN) {
            const int r = rowptr[idx] + off;
            rowptr[idx] = r;
            cursor[idx] = r;
        }
    }
}

__global__ __launch_bounds__(256) void fill_kernel(
    const int* __restrict__ ei, int* __restrict__ cursor, int* __restrict__ csr_src)
{
    const int e = blockIdx.x * 256 + threadIdx.x;
    if (e == 0) { csr_src[ET] = 0; csr_src[ET + 1] = 0; }   // pipeline pad
    if (e >= ET) return;
    int s, d;
    if (e < NE) { s = ei[e]; d = ei[NE + e]; }
    else        { s = e - NE; d = s; }
    csr_src[atomicAdd(&cursor[d], 1)] = s;
}

// ---------------------------------------------------------------------------
// Gather: one wave per dst node; lane group h = lane>>4 handles only head h.
// Depth-2 register pipeline: at iter j, loads for j+1 (As, Xh via s from the
// previous stage) and the index for j+2 are in flight; compute uses registers
// loaded a full iteration earlier. csr_src padded -> no branches in loop.
// ---------------------------------------------------------------------------
__global__ __launch_bounds__(256) void gather_kernel(
    const int* __restrict__ rowptr, const int* __restrict__ csr_src,
    const float* __restrict__ As, const float* __restrict__ Ad,
    const __half* __restrict__ Xh, const float* __restrict__ bias,
    float* __restrict__ out)
{
    const int gid  = blockIdx.x * 256 + threadIdx.x;
    const int w    = gid >> 6;
    const int lane = gid & 63;
    if (w >= NN) return;

    const int beg = rowptr[w];
    const int end = rowptr[w + 1];
    const int h   = lane >> 4;

    const float adh = Ad[w * 4 + h];
    float4 acc = {0.f, 0.f, 0.f, 0.f};
    float den = 0.f;

    // prologue: stage A = edge beg, index for edge beg+1
    int    sA = csr_src[beg];                       // beg < ET always (deg>=1)
    float  aA = As[sA * 4 + h];
    float2 xA = *reinterpret_cast<const float2*>(Xh + (size_t)sA * HC + 4 * lane);
    int    sB = csr_src[beg + 1];                   // beg+1 <= ET (padded)

    for (int j = beg; j < end; ++j) {
        // issue loads for stage B (consumed next iter) + index for j+2
        const float  aB = As[sB * 4 + h];
        const float2 xB = *reinterpret_cast<const float2*>(
            Xh + (size_t)sB * HC + 4 * lane);
        const int    sC = csr_src[j + 2];           // j+2 <= ET+1 (padded)

        // compute stage A (registers from previous iteration)
        float lg = aA + adh;
        lg = lg > 0.f ? lg : 0.2f * lg;
        const float ex = __expf(lg);
        den += ex;
        const __half2* h2 = reinterpret_cast<const __half2*>(&xA);
        const float2 lo = __half22float2(h2[0]);
        const float2 hi = __half22float2(h2[1]);
        acc.x = fmaf(ex, lo.x, acc.x);
        acc.y = fmaf(ex, lo.y, acc.y);
        acc.z = fmaf(ex, hi.x, acc.z);
        acc.w = fmaf(ex, hi.y, acc.w);

        aA = aB; xA = xB; sB = sC;                  // rotate pipeline
    }

    const float inv = 0.25f * __frcp_rn(den);
    acc.x *= inv; acc.y *= inv; acc.z *= inv; acc.w *= inv;

    // sum across the 4 head-lane-groups (lanes l, l^16, l^32, l^48 share channels)
    acc.x += __shfl_xor(acc.x, 16); acc.x += __shfl_xor(acc.x, 32);
    acc.y += __shfl_xor(acc.y, 16); acc.y += __shfl_xor(acc.y, 32);
    acc.z += __shfl_xor(acc.z, 16); acc.z += __shfl_xor(acc.z, 32);
    acc.w += __shfl_xor(acc.w, 16); acc.w += __shfl_xor(acc.w, 32);

    if (lane < 16) {
        const float4 b = *reinterpret_cast<const float4*>(&bias[4 * lane]);
        float4 o;
        o.x = acc.x + b.x; o.y = acc.y + b.y;
        o.z = acc.z + b.z; o.w = acc.w + b.w;
        *reinterpret_cast<float4*>(&out[(size_t)w * OC + 4 * lane]) = o;
    }
}

extern "C" void kernel_launch(void* const* d_in, const int* in_sizes, int n_in,
                              void* d_out, int out_size, void* d_ws, size_t ws_size,
                              hipStream_t stream)
{
    const float* feat = (const float*)d_in[0];
    const int*   ei   = (const int*)d_in[1];
    const float* lw   = (const float*)d_in[2];
    const float* as   = (const float*)d_in[3];
    const float* ad   = (const float*)d_in[4];
    const float* bias = (const float*)d_in[5];
    float* out = (float*)d_out;

    constexpr int NSB = (NN + 1023) / 1024;   // 49 scan blocks

    char* ws = (char*)d_ws;
    __half* Xh     = (__half*)ws;  ws += (size_t)NN * HC * 2;
    __half* Wt     = (__half*)ws;  ws += (size_t)HC * IC * 2;
    float*  Asrc   = (float*)ws;   ws += (size_t)NN * 4 * 4;
    float*  Adst   = (float*)ws;   ws += (size_t)NN * 4 * 4;
    int*    deg    = (int*)ws;     ws += (size_t)NN * 4;      // zeroed
    int*    rowptr = (int*)ws;     ws += (size_t)(NN + 1) * 4;
    int*    cursor = (int*)ws;     ws += (size_t)NN * 4;
    int*    bsum   = (int*)ws;     ws += (size_t)64 * 4;
    int*    csrsrc = (int*)ws;     ws += (size_t)(ET + 2) * 4;

    (void)hipMemsetAsync(deg, 0, sizeof(int) * (size_t)NN, stream);

    prep_wt<<<IC, HC, 0, stream>>>(lw, Wt);
    proj_mfma<<<(NN + 63) / 64, 256, 0, stream>>>(feat, Wt, as, ad, Xh, Asrc, Adst);
    hist_kernel<<<(ET + 255) / 256, 256, 0, stream>>>(ei, deg);
    scan1<<<NSB, 256, 0, stream>>>(deg, rowptr, bsum);
    scan2<<<1, 64, 0, stream>>>(bsum, rowptr + NN, NSB);
    scan3<<<NSB, 256, 0, stream>>>(rowptr, bsum, cursor);
    fill_kernel<<<(ET + 255) / 256, 256, 0, stream>>>(ei, cursor, csrsrc);
    gather_kernel<<<(NN * 64 + 255) / 256, 256, 0, stream>>>(
        rowptr, csrsrc, Asrc, Adst, Xh, bias, out);
}

// Round 8
// 195.611 us; speedup vs baseline: 1.1358x; 1.1330x over previous
//
#include <hip/hip_runtime.h>
#include <hip/hip_fp16.h>

typedef _Float16 f16x8 __attribute__((ext_vector_type(8)));
typedef _Float16 f16x4 __attribute__((ext_vector_type(4)));
typedef float    f32x4 __attribute__((ext_vector_type(4)));

constexpr int NN = 50000;        // nodes
constexpr int NE = 800000;       // edges (before self-loops)
constexpr int ET = NE + NN;      // edges + self-loops
constexpr int IC = 128;          // in channels
constexpr int HC = 256;          // heads * out_ch
constexpr int OC = 64;           // out channels

// ---------------------------------------------------------------------------
// Prep: Wt[m][k] = lin_w[k][m] as fp16 (A-operand, L2-resident 64KB)
// ---------------------------------------------------------------------------
__global__ void prep_wt(const float* __restrict__ w, __half* __restrict__ wt)
{
    const int k = blockIdx.x;      // 128
    const int m = threadIdx.x;     // 256
    wt[m * IC + k] = __float2half(w[k * HC + m]);
}

// ---------------------------------------------------------------------------
// Proj via MFMA + fused per-head logits. Output staged through LDS so global
// stores are full 512B node-rows. (Kept from R6 — non-gather time improved.)
// ---------------------------------------------------------------------------
__global__ __launch_bounds__(256) void proj_mfma(
    const float* __restrict__ feat, const __half* __restrict__ wt,
    const float* __restrict__ att_s, const float* __restrict__ att_d,
    __half* __restrict__ Xh, float* __restrict__ As, float* __restrict__ Ad)
{
    __shared__ _Float16 sf[64 * 128];        // input tile
    __shared__ _Float16 so[64 * 260];        // output stage (+4ch pad)
    const int t  = threadIdx.x;
    const int w  = t >> 6;
    const int l  = t & 63;
    const int n0 = blockIdx.x * 64;

    {
        const int r  = t >> 2;
        const int gr = min(n0 + r, NN - 1);
        const float* src = feat + (size_t)gr * IC + (t & 3) * 32;
#pragma unroll
        for (int i = 0; i < 4; ++i) {
            const float4 f0 = *reinterpret_cast<const float4*>(src + i * 8);
            const float4 f1 = *reinterpret_cast<const float4*>(src + i * 8 + 4);
            f16x8 hv;
            hv[0] = (_Float16)f0.x; hv[1] = (_Float16)f0.y;
            hv[2] = (_Float16)f0.z; hv[3] = (_Float16)f0.w;
            hv[4] = (_Float16)f1.x; hv[5] = (_Float16)f1.y;
            hv[6] = (_Float16)f1.z; hv[7] = (_Float16)f1.w;
            const int cc = (t & 3) * 4 + i;
            *reinterpret_cast<f16x8*>(&sf[(r * 16 + (cc ^ (r & 7))) * 8]) = hv;
        }
    }
    __syncthreads();

    const int lhi = l >> 4, llo = l & 15;
    f32x4 acc[4][4] = {};   // [mg(channel)][ng(node)]

#pragma unroll
    for (int ks = 0; ks < 4; ++ks) {
        f16x8 a[4], b[4];
#pragma unroll
        for (int mg = 0; mg < 4; ++mg) {
            const int row = w * 64 + mg * 16 + llo;            // channel
            a[mg] = *reinterpret_cast<const f16x8*>(
                wt + (size_t)row * IC + ks * 32 + lhi * 8);
        }
#pragma unroll
        for (int ng = 0; ng < 4; ++ng) {
            const int rr = ng * 16 + llo;                      // node in tile
            const int cc = ks * 4 + lhi;
            b[ng] = *reinterpret_cast<const f16x8*>(
                &sf[(rr * 16 + (cc ^ (rr & 7))) * 8]);
        }
#pragma unroll
        for (int mg = 0; mg < 4; ++mg)
#pragma unroll
            for (int ng = 0; ng < 4; ++ng)
                acc[mg][ng] = __builtin_amdgcn_mfma_f32_16x16x32_f16(
                    a[mg], b[ng], acc[mg][ng], 0, 0, 0);
    }

    float4 avs[4], avd[4];
#pragma unroll
    for (int mg = 0; mg < 4; ++mg) {
        const int ch = w * 64 + mg * 16 + 4 * lhi;
        avs[mg] = *reinterpret_cast<const float4*>(att_s + ch);
        avd[mg] = *reinterpret_cast<const float4*>(att_d + ch);
    }

#pragma unroll
    for (int ng = 0; ng < 4; ++ng) {
        const int n = n0 + ng * 16 + llo;
        float ps = 0.f, pd = 0.f;
#pragma unroll
        for (int mg = 0; mg < 4; ++mg) {
            const f32x4 v = acc[mg][ng];
            ps += v[0] * avs[mg].x + v[1] * avs[mg].y
                + v[2] * avs[mg].z + v[3] * avs[mg].w;
            pd += v[0] * avd[mg].x + v[1] * avd[mg].y
                + v[2] * avd[mg].z + v[3] * avd[mg].w;
            f16x4 pk;
            pk[0] = (_Float16)v[0]; pk[1] = (_Float16)v[1];
            pk[2] = (_Float16)v[2]; pk[3] = (_Float16)v[3];
            *reinterpret_cast<f16x4*>(
                &so[(ng * 16 + llo) * 260 + w * 64 + mg * 16 + 4 * lhi]) = pk;
        }
        ps += __shfl_xor(ps, 16); ps += __shfl_xor(ps, 32);
        pd += __shfl_xor(pd, 16); pd += __shfl_xor(pd, 32);
        if (lhi == 0 && n < NN) {
            As[n * 4 + w] = ps;
            Ad[n * 4 + w] = pd;
        }
    }
    __syncthreads();

#pragma unroll
    for (int rr = 0; rr < 16; ++rr) {
        const int r = w * 16 + rr;
        const int n = n0 + r;
        if (n < NN)
            *reinterpret_cast<f16x4*>(&Xh[(size_t)n * HC + 4 * l]) =
                *reinterpret_cast<const f16x4*>(&so[r * 260 + 4 * l]);
    }
}

// ---------------------------------------------------------------------------
// CSR build: histogram, hierarchical scan (3 small kernels), fill
// ---------------------------------------------------------------------------
__global__ __launch_bounds__(256) void hist_kernel(
    const int* __restrict__ ei, int* __restrict__ deg)
{
    const int e = blockIdx.x * 256 + threadIdx.x;
    if (e >= ET) return;
    const int d = (e < NE) ? ei[NE + e] : (e - NE);
    atomicAdd(&deg[d], 1);
}

__global__ __launch_bounds__(256) void scan1(
    const int* __restrict__ deg, int* __restrict__ rowptr, int* __restrict__ bsum)
{
    __shared__ int sh[256];
    const int t = threadIdx.x;
    const int base = blockIdx.x * 1024 + t * 4;
    int4 v = {0, 0, 0, 0};
    if (base + 3 < NN) v = *reinterpret_cast<const int4*>(deg + base);
    else {
        if (base     < NN) v.x = deg[base];
        if (base + 1 < NN) v.y = deg[base + 1];
        if (base + 2 < NN) v.z = deg[base + 2];
    }
    sh[t] = v.x + v.y + v.z + v.w;
    __syncthreads();
    for (int o = 1; o < 256; o <<= 1) {
        const int u = (t >= o) ? sh[t - o] : 0;
        __syncthreads();
        sh[t] += u;
        __syncthreads();
    }
    const int excl = t ? sh[t - 1] : 0;
    int4 e;
    e.x = excl; e.y = excl + v.x; e.z = e.y + v.y; e.w = e.z + v.z;
    if (base + 3 < NN) *reinterpret_cast<int4*>(rowptr + base) = e;
    else {
        if (base     < NN) rowptr[base]     = e.x;
        if (base + 1 < NN) rowptr[base + 1] = e.y;
        if (base + 2 < NN) rowptr[base + 2] = e.z;
    }
    if (t == 255) bsum[blockIdx.x] = sh[255];
}

__global__ void scan2(int* __restrict__ bsum, int* __restrict__ rowptr_end, int nb)
{
    const int t = threadIdx.x;   // 64
    const int v = (t < nb) ? bsum[t] : 0;
    int inc = v;
#pragma unroll
    for (int o = 1; o < 64; o <<= 1) {
        const int u = __shfl_up(inc, o);
        if (t >= o) inc += u;
    }
    if (t < nb) bsum[t] = inc - v;            // exclusive block offset
    if (t == 63) rowptr_end[0] = inc;         // total = ET
}

__global__ __launch_bounds__(256) void scan3(
    int* __restrict__ rowptr, const int* __restrict__ bsum, int* __restrict__ cursor)
{
    const int off  = bsum[blockIdx.x];
    const int base = blockIdx.x * 1024 + threadIdx.x * 4;
#pragma unroll
    for (int i = 0; i < 4; ++i) {
        const int idx = base + i;
        if (idx < NN) {
            const int r = rowptr[idx] + off;
            rowptr[idx] = r;
            cursor[idx] = r;
        }
    }
}

__global__ __launch_bounds__(256) void fill_kernel(
    const int* __restrict__ ei, int* __restrict__ cursor, int* __restrict__ csr_src)
{
    const int e = blockIdx.x * 256 + threadIdx.x;
    if (e < 4) csr_src[ET + e] = 0;            // pad: branchless batch-4 tail
    if (e >= ET) return;
    int s, d;
    if (e < NE) { s = ei[e]; d = ei[NE + e]; }
    else        { s = e - NE; d = s; }
    csr_src[atomicAdd(&cursor[d], 1)] = s;
}

// ---------------------------------------------------------------------------
// Gather: one wave per dst node; lane group h = lane>>4 handles only head h.
// Batch-4 edges per iteration: 12 INDEPENDENT loads issue before any
// consumption (no loop-carried rotation -> compiler counts vmcnt, overlaps
// iterations). Tail masked by zeroing ex; csr_src padded with 4 zeros.
// ---------------------------------------------------------------------------
__global__ __launch_bounds__(256) void gather_kernel(
    const int* __restrict__ rowptr, const int* __restrict__ csr_src,
    const float* __restrict__ As, const float* __restrict__ Ad,
    const __half* __restrict__ Xh, const float* __restrict__ bias,
    float* __restrict__ out)
{
    const int gid  = blockIdx.x * 256 + threadIdx.x;
    const int w    = gid >> 6;
    const int lane = gid & 63;
    if (w >= NN) return;

    const int beg = rowptr[w];
    const int end = rowptr[w + 1];
    const int h   = lane >> 4;

    const float adh = Ad[w * 4 + h];
    float4 acc = {0.f, 0.f, 0.f, 0.f};
    float den = 0.f;

    for (int j = beg; j < end; j += 4) {
        const int s0 = csr_src[j];
        const int s1 = csr_src[j + 1];
        const int s2 = csr_src[j + 2];
        const int s3 = csr_src[j + 3];

        const float a0 = As[s0 * 4 + h];
        const float a1 = As[s1 * 4 + h];
        const float a2 = As[s2 * 4 + h];
        const float a3 = As[s3 * 4 + h];
        const float2 x0 = *reinterpret_cast<const float2*>(Xh + (size_t)s0 * HC + 4 * lane);
        const float2 x1 = *reinterpret_cast<const float2*>(Xh + (size_t)s1 * HC + 4 * lane);
        const float2 x2 = *reinterpret_cast<const float2*>(Xh + (size_t)s2 * HC + 4 * lane);
        const float2 x3 = *reinterpret_cast<const float2*>(Xh + (size_t)s3 * HC + 4 * lane);

        float l0 = a0 + adh; l0 = l0 > 0.f ? l0 : 0.2f * l0;
        float l1 = a1 + adh; l1 = l1 > 0.f ? l1 : 0.2f * l1;
        float l2 = a2 + adh; l2 = l2 > 0.f ? l2 : 0.2f * l2;
        float l3 = a3 + adh; l3 = l3 > 0.f ? l3 : 0.2f * l3;
        float e0 = __expf(l0);
        float e1 = (j + 1 < end) ? __expf(l1) : 0.f;
        float e2 = (j + 2 < end) ? __expf(l2) : 0.f;
        float e3 = (j + 3 < end) ? __expf(l3) : 0.f;
        den += (e0 + e1) + (e2 + e3);

        const __half2* p0 = reinterpret_cast<const __half2*>(&x0);
        const __half2* p1 = reinterpret_cast<const __half2*>(&x1);
        const __half2* p2 = reinterpret_cast<const __half2*>(&x2);
        const __half2* p3 = reinterpret_cast<const __half2*>(&x3);
        float2 lo, hi;
        lo = __half22float2(p0[0]); hi = __half22float2(p0[1]);
        acc.x = fmaf(e0, lo.x, acc.x); acc.y = fmaf(e0, lo.y, acc.y);
        acc.z = fmaf(e0, hi.x, acc.z); acc.w = fmaf(e0, hi.y, acc.w);
        lo = __half22float2(p1[0]); hi = __half22float2(p1[1]);
        acc.x = fmaf(e1, lo.x, acc.x); acc.y = fmaf(e1, lo.y, acc.y);
        acc.z = fmaf(e1, hi.x, acc.z); acc.w = fmaf(e1, hi.y, acc.w);
        lo = __half22float2(p2[0]); hi = __half22float2(p2[1]);
        acc.x = fmaf(e2, lo.x, acc.x); acc.y = fmaf(e2, lo.y, acc.y);
        acc.z = fmaf(e2, hi.x, acc.z); acc.w = fmaf(e2, hi.y, acc.w);
        lo = __half22float2(p3[0]); hi = __half22float2(p3[1]);
        acc.x = fmaf(e3, lo.x, acc.x); acc.y = fmaf(e3, lo.y, acc.y);
        acc.z = fmaf(e3, hi.x, acc.z); acc.w = fmaf(e3, hi.y, acc.w);
    }

    const float inv = 0.25f * __frcp_rn(den);
    acc.x *= inv; acc.y *= inv; acc.z *= inv; acc.w *= inv;

    acc.x += __shfl_xor(acc.x, 16); acc.x += __shfl_xor(acc.x, 32);
    acc.y += __shfl_xor(acc.y, 16); acc.y += __shfl_xor(acc.y, 32);
    acc.z += __shfl_xor(acc.z, 16); acc.z += __shfl_xor(acc.z, 32);
    acc.w += __shfl_xor(acc.w, 16); acc.w += __shfl_xor(acc.w, 32);

    if (lane < 16) {
        const float4 b = *reinterpret_cast<const float4*>(&bias[4 * lane]);
        float4 o;
        o.x = acc.x + b.x; o.y = acc.y + b.y;
        o.z = acc.z + b.z; o.w = acc.w + b.w;
        *reinterpret_cast<float4*>(&out[(size_t)w * OC + 4 * lane]) = o;
    }
}

extern "C" void kernel_launch(void* const* d_in, const int* in_sizes, int n_in,
                              void* d_out, int out_size, void* d_ws, size_t ws_size,
                              hipStream_t stream)
{
    const float* feat = (const float*)d_in[0];
    const int*   ei   = (const int*)d_in[1];
    const float* lw   = (const float*)d_in[2];
    const float* as   = (const float*)d_in[3];
    const float* ad   = (const float*)d_in[4];
    const float* bias = (const float*)d_in[5];
    float* out = (float*)d_out;

    constexpr int NSB = (NN + 1023) / 1024;   // 49 scan blocks

    char* ws = (char*)d_ws;
    __half* Xh     = (__half*)ws;  ws += (size_t)NN * HC * 2;
    __half* Wt     = (__half*)ws;  ws += (size_t)HC * IC * 2;
    float*  Asrc   = (float*)ws;   ws += (size_t)NN * 4 * 4;
    float*  Adst   = (float*)ws;   ws += (size_t)NN * 4 * 4;
    int*    deg    = (int*)ws;     ws += (size_t)NN * 4;      // zeroed
    int*    rowptr = (int*)ws;     ws += (size_t)(NN + 1) * 4;
    int*    cursor = (int*)ws;     ws += (size_t)NN * 4;
    int*    bsum   = (int*)ws;     ws += (size_t)64 * 4;
    int*    csrsrc = (int*)ws;     ws += (size_t)(ET + 4) * 4;

    (void)hipMemsetAsync(deg, 0, sizeof(int) * (size_t)NN, stream);

    prep_wt<<<IC, HC, 0, stream>>>(lw, Wt);
    proj_mfma<<<(NN + 63) / 64, 256, 0, stream>>>(feat, Wt, as, ad, Xh, Asrc, Adst);
    hist_kernel<<<(ET + 255) / 256, 256, 0, stream>>>(ei, deg);
    scan1<<<NSB, 256, 0, stream>>>(deg, rowptr, bsum);
    scan2<<<1, 64, 0, stream>>>(bsum, rowptr + NN, NSB);
    scan3<<<NSB, 256, 0, stream>>>(rowptr, bsum, cursor);
    fill_kernel<<<(ET + 255) / 256, 256, 0, stream>>>(ei, cursor, csrsrc);
    gather_kernel<<<(NN * 64 + 255) / 256, 256, 0, stream>>>(
        rowptr, csrsrc, Asrc, Adst, Xh, bias, out);
}

// Round 9
// 185.076 us; speedup vs baseline: 1.2004x; 1.0569x over previous
//
#include <hip/hip_runtime.h>
#include <hip/hip_fp16.h>

typedef _Float16 f16x8 __attribute__((ext_vector_type(8)));
typedef _Float16 f16x4 __attribute__((ext_vector_type(4)));
typedef float    f32x4 __attribute__((ext_vector_type(4)));

constexpr int NN = 50000;        // nodes
constexpr int NE = 800000;       // real edges (self-loops handled inline)
constexpr int IC = 128;          // in channels
constexpr int HC = 256;          // heads * out_ch
constexpr int OC = 64;           // out channels

// ---------------------------------------------------------------------------
// Fused prep: blocks 0..127 transpose lin_w -> Wt fp16; remaining blocks
// histogram dst over the 800K real edges; also zero the csr pad.
// ---------------------------------------------------------------------------
__global__ __launch_bounds__(256) void prep_hist(
    const float* __restrict__ w, __half* __restrict__ wt,
    const int* __restrict__ ei, int* __restrict__ deg,
    int* __restrict__ csr_src)
{
    if (blockIdx.x < IC) {
        const int k = blockIdx.x;
        const int m = threadIdx.x;
        wt[m * IC + k] = __float2half(w[k * HC + m]);
        return;
    }
    const int e = (blockIdx.x - IC) * 256 + threadIdx.x;
    if (e < 8) csr_src[NE + e] = 0;               // pad for batch-8 tail
    if (e >= NE) return;
    atomicAdd(&deg[ei[NE + e]], 1);
}

// ---------------------------------------------------------------------------
// Proj via MFMA + fused per-head logits; output staged through LDS for
// coalesced 512B row stores. (Structure from R6/R7 — verified.)
// ---------------------------------------------------------------------------
__global__ __launch_bounds__(256) void proj_mfma(
    const float* __restrict__ feat, const __half* __restrict__ wt,
    const float* __restrict__ att_s, const float* __restrict__ att_d,
    __half* __restrict__ Xh, float* __restrict__ As, float* __restrict__ Ad)
{
    __shared__ _Float16 sf[64 * 128];        // input tile
    __shared__ _Float16 so[64 * 260];        // output stage (+4ch pad)
    const int t  = threadIdx.x;
    const int w  = t >> 6;
    const int l  = t & 63;
    const int n0 = blockIdx.x * 64;

    {
        const int r  = t >> 2;
        const int gr = min(n0 + r, NN - 1);
        const float* src = feat + (size_t)gr * IC + (t & 3) * 32;
#pragma unroll
        for (int i = 0; i < 4; ++i) {
            const float4 f0 = *reinterpret_cast<const float4*>(src + i * 8);
            const float4 f1 = *reinterpret_cast<const float4*>(src + i * 8 + 4);
            f16x8 hv;
            hv[0] = (_Float16)f0.x; hv[1] = (_Float16)f0.y;
            hv[2] = (_Float16)f0.z; hv[3] = (_Float16)f0.w;
            hv[4] = (_Float16)f1.x; hv[5] = (_Float16)f1.y;
            hv[6] = (_Float16)f1.z; hv[7] = (_Float16)f1.w;
            const int cc = (t & 3) * 4 + i;
            *reinterpret_cast<f16x8*>(&sf[(r * 16 + (cc ^ (r & 7))) * 8]) = hv;
        }
    }
    __syncthreads();

    const int lhi = l >> 4, llo = l & 15;
    f32x4 acc[4][4] = {};   // [mg(channel)][ng(node)]

#pragma unroll
    for (int ks = 0; ks < 4; ++ks) {
        f16x8 a[4], b[4];
#pragma unroll
        for (int mg = 0; mg < 4; ++mg) {
            const int row = w * 64 + mg * 16 + llo;            // channel
            a[mg] = *reinterpret_cast<const f16x8*>(
                wt + (size_t)row * IC + ks * 32 + lhi * 8);
        }
#pragma unroll
        for (int ng = 0; ng < 4; ++ng) {
            const int rr = ng * 16 + llo;                      // node in tile
            const int cc = ks * 4 + lhi;
            b[ng] = *reinterpret_cast<const f16x8*>(
                &sf[(rr * 16 + (cc ^ (rr & 7))) * 8]);
        }
#pragma unroll
        for (int mg = 0; mg < 4; ++mg)
#pragma unroll
            for (int ng = 0; ng < 4; ++ng)
                acc[mg][ng] = __builtin_amdgcn_mfma_f32_16x16x32_f16(
                    a[mg], b[ng], acc[mg][ng], 0, 0, 0);
    }

    float4 avs[4], avd[4];
#pragma unroll
    for (int mg = 0; mg < 4; ++mg) {
        const int ch = w * 64 + mg * 16 + 4 * lhi;
        avs[mg] = *reinterpret_cast<const float4*>(att_s + ch);
        avd[mg] = *reinterpret_cast<const float4*>(att_d + ch);
    }

#pragma unroll
    for (int ng = 0; ng < 4; ++ng) {
        const int n = n0 + ng * 16 + llo;
        float ps = 0.f, pd = 0.f;
#pragma unroll
        for (int mg = 0; mg < 4; ++mg) {
            const f32x4 v = acc[mg][ng];
            ps += v[0] * avs[mg].x + v[1] * avs[mg].y
                + v[2] * avs[mg].z + v[3] * avs[mg].w;
            pd += v[0] * avd[mg].x + v[1] * avd[mg].y
                + v[2] * avd[mg].z + v[3] * avd[mg].w;
            f16x4 pk;
            pk[0] = (_Float16)v[0]; pk[1] = (_Float16)v[1];
            pk[2] = (_Float16)v[2]; pk[3] = (_Float16)v[3];
            *reinterpret_cast<f16x4*>(
                &so[(ng * 16 + llo) * 260 + w * 64 + mg * 16 + 4 * lhi]) = pk;
        }
        ps += __shfl_xor(ps, 16); ps += __shfl_xor(ps, 32);
        pd += __shfl_xor(pd, 16); pd += __shfl_xor(pd, 32);
        if (lhi == 0 && n < NN) {
            As[n * 4 + w] = ps;
            Ad[n * 4 + w] = pd;
        }
    }
    __syncthreads();

#pragma unroll
    for (int rr = 0; rr < 16; ++rr) {
        const int r = w * 16 + rr;
        const int n = n0 + r;
        if (n < NN)
            *reinterpret_cast<f16x4*>(&Xh[(size_t)n * HC + 4 * l]) =
                *reinterpret_cast<const f16x4*>(&so[r * 260 + 4 * l]);
    }
}

// ---------------------------------------------------------------------------
// Hierarchical scan over deg (NN entries), then fill (real edges only)
// ---------------------------------------------------------------------------
__global__ __launch_bounds__(256) void scan1(
    const int* __restrict__ deg, int* __restrict__ rowptr, int* __restrict__ bsum)
{
    __shared__ int sh[256];
    const int t = threadIdx.x;
    const int base = blockIdx.x * 1024 + t * 4;
    int4 v = {0, 0, 0, 0};
    if (base + 3 < NN) v = *reinterpret_cast<const int4*>(deg + base);
    else {
        if (base     < NN) v.x = deg[base];
        if (base + 1 < NN) v.y = deg[base + 1];
        if (base + 2 < NN) v.z = deg[base + 2];
    }
    sh[t] = v.x + v.y + v.z + v.w;
    __syncthreads();
    for (int o = 1; o < 256; o <<= 1) {
        const int u = (t >= o) ? sh[t - o] : 0;
        __syncthreads();
        sh[t] += u;
        __syncthreads();
    }
    const int excl = t ? sh[t - 1] : 0;
    int4 e;
    e.x = excl; e.y = excl + v.x; e.z = e.y + v.y; e.w = e.z + v.z;
    if (base + 3 < NN) *reinterpret_cast<int4*>(rowptr + base) = e;
    else {
        if (base     < NN) rowptr[base]     = e.x;
        if (base + 1 < NN) rowptr[base + 1] = e.y;
        if (base + 2 < NN) rowptr[base + 2] = e.z;
    }
    if (t == 255) bsum[blockIdx.x] = sh[255];
}

__global__ void scan2(int* __restrict__ bsum, int* __restrict__ rowptr_end, int nb)
{
    const int t = threadIdx.x;   // 64
    const int v = (t < nb) ? bsum[t] : 0;
    int inc = v;
#pragma unroll
    for (int o = 1; o < 64; o <<= 1) {
        const int u = __shfl_up(inc, o);
        if (t >= o) inc += u;
    }
    if (t < nb) bsum[t] = inc - v;            // exclusive block offset
    if (t == 63) rowptr_end[0] = inc;         // total = NE
}

__global__ __launch_bounds__(256) void scan3(
    int* __restrict__ rowptr, const int* __restrict__ bsum, int* __restrict__ cursor)
{
    const int off  = bsum[blockIdx.x];
    const int base = blockIdx.x * 1024 + threadIdx.x * 4;
#pragma unroll
    for (int i = 0; i < 4; ++i) {
        const int idx = base + i;
        if (idx < NN) {
            const int r = rowptr[idx] + off;
            rowptr[idx] = r;
            cursor[idx] = r;
        }
    }
}

__global__ __launch_bounds__(256) void fill_kernel(
    const int* __restrict__ ei, int* __restrict__ cursor, int* __restrict__ csr_src)
{
    const int e = blockIdx.x * 256 + threadIdx.x;
    if (e >= NE) return;
    const int s = ei[e];
    const int d = ei[NE + e];
    csr_src[atomicAdd(&cursor[d], 1)] = s;
}

// ---------------------------------------------------------------------------
// Gather: one wave per dst node; lane group h = lane>>4 handles only head h.
// Self-loop handled inline (s = w, always present per reference). Real edges
// batch-8: 24 independent loads in flight before consumption; tail masked.
// ---------------------------------------------------------------------------
__global__ __launch_bounds__(256) void gather_kernel(
    const int* __restrict__ rowptr, const int* __restrict__ csr_src,
    const float* __restrict__ As, const float* __restrict__ Ad,
    const __half* __restrict__ Xh, const float* __restrict__ bias,
    float* __restrict__ out)
{
    const int gid  = blockIdx.x * 256 + threadIdx.x;
    const int w    = gid >> 6;
    const int lane = gid & 63;
    if (w >= NN) return;

    const int beg = rowptr[w];
    const int end = rowptr[w + 1];
    const int h   = lane >> 4;

    const float adh = Ad[w * 4 + h];
    float4 acc = {0.f, 0.f, 0.f, 0.f};
    float den = 0.f;

    // inline self-loop: s = w (block-contiguous Xh rows -> cheap)
    {
        float lg = As[w * 4 + h] + adh;
        lg = lg > 0.f ? lg : 0.2f * lg;
        const float ex = __expf(lg);
        den = ex;
        const float2 xw = *reinterpret_cast<const float2*>(
            Xh + (size_t)w * HC + 4 * lane);
        const __half2* p = reinterpret_cast<const __half2*>(&xw);
        const float2 lo = __half22float2(p[0]);
        const float2 hi = __half22float2(p[1]);
        acc.x = ex * lo.x; acc.y = ex * lo.y;
        acc.z = ex * hi.x; acc.w = ex * hi.y;
    }

    for (int j = beg; j < end; j += 8) {
        int s[8]; float a[8]; float2 x[8];
#pragma unroll
        for (int i = 0; i < 8; ++i) s[i] = csr_src[j + i];
#pragma unroll
        for (int i = 0; i < 8; ++i) a[i] = As[s[i] * 4 + h];
#pragma unroll
        for (int i = 0; i < 8; ++i)
            x[i] = *reinterpret_cast<const float2*>(
                Xh + (size_t)s[i] * HC + 4 * lane);
#pragma unroll
        for (int i = 0; i < 8; ++i) {
            float lg = a[i] + adh;
            lg = lg > 0.f ? lg : 0.2f * lg;
            const float ex = (i == 0 || j + i < end) ? __expf(lg) : 0.f;
            den += ex;
            const __half2* p = reinterpret_cast<const __half2*>(&x[i]);
            const float2 lo = __half22float2(p[0]);
            const float2 hi = __half22float2(p[1]);
            acc.x = fmaf(ex, lo.x, acc.x); acc.y = fmaf(ex, lo.y, acc.y);
            acc.z = fmaf(ex, hi.x, acc.z); acc.w = fmaf(ex, hi.y, acc.w);
        }
    }

    const float inv = 0.25f * __frcp_rn(den);
    acc.x *= inv; acc.y *= inv; acc.z *= inv; acc.w *= inv;

    acc.x += __shfl_xor(acc.x, 16); acc.x += __shfl_xor(acc.x, 32);
    acc.y += __shfl_xor(acc.y, 16); acc.y += __shfl_xor(acc.y, 32);
    acc.z += __shfl_xor(acc.z, 16); acc.z += __shfl_xor(acc.z, 32);
    acc.w += __shfl_xor(acc.w, 16); acc.w += __shfl_xor(acc.w, 32);

    if (lane < 16) {
        const float4 b = *reinterpret_cast<const float4*>(&bias[4 * lane]);
        float4 o;
        o.x = acc.x + b.x; o.y = acc.y + b.y;
        o.z = acc.z + b.z; o.w = acc.w + b.w;
        *reinterpret_cast<float4*>(&out[(size_t)w * OC + 4 * lane]) = o;
    }
}

extern "C" void kernel_launch(void* const* d_in, const int* in_sizes, int n_in,
                              void* d_out, int out_size, void* d_ws, size_t ws_size,
                              hipStream_t stream)
{
    const float* feat = (const float*)d_in[0];
    const int*   ei   = (const int*)d_in[1];
    const float* lw   = (const float*)d_in[2];
    const float* as   = (const float*)d_in[3];
    const float* ad   = (const float*)d_in[4];
    const float* bias = (const float*)d_in[5];
    float* out = (float*)d_out;

    constexpr int NSB = (NN + 1023) / 1024;   // 49 scan blocks

    char* ws = (char*)d_ws;
    __half* Xh     = (__half*)ws;  ws += (size_t)NN * HC * 2;
    __half* Wt     = (__half*)ws;  ws += (size_t)HC * IC * 2;
    float*  Asrc   = (float*)ws;   ws += (size_t)NN * 4 * 4;
    float*  Adst   = (float*)ws;   ws += (size_t)NN * 4 * 4;
    int*    deg    = (int*)ws;     ws += (size_t)NN * 4;      // zeroed
    int*    rowptr = (int*)ws;     ws += (size_t)(NN + 1) * 4;
    int*    cursor = (int*)ws;     ws += (size_t)NN * 4;
    int*    bsum   = (int*)ws;     ws += (size_t)64 * 4;
    int*    csrsrc = (int*)ws;     ws += (size_t)(NE + 8) * 4;

    (void)hipMemsetAsync(deg, 0, sizeof(int) * (size_t)NN, stream);

    prep_hist<<<IC + (NE + 255) / 256, 256, 0, stream>>>(lw, Wt, ei, deg, csrsrc);
    proj_mfma<<<(NN + 63) / 64, 256, 0, stream>>>(feat, Wt, as, ad, Xh, Asrc, Adst);
    scan1<<<NSB, 256, 0, stream>>>(deg, rowptr, bsum);
    scan2<<<1, 64, 0, stream>>>(bsum, rowptr + NN, NSB);
    scan3<<<NSB, 256, 0, stream>>>(rowptr, bsum, cursor);
    fill_kernel<<<(NE + 255) / 256, 256, 0, stream>>>(ei, cursor, csrsrc);
    gather_kernel<<<(NN * 64 + 255) / 256, 256, 0, stream>>>(
        rowptr, csrsrc, Asrc, Adst, Xh, bias, out);
}